// Round 11
// baseline (459.199 us; speedup 1.0000x reference)
//
#include <hip/hip_runtime.h>

#define T_TOK 4096
#define HD 2048
#define NE 8
#define NI 1408

typedef __bf16 bf16x8 __attribute__((ext_vector_type(8)));
typedef float f32x4 __attribute__((ext_vector_type(4)));
typedef unsigned short ushort8 __attribute__((ext_vector_type(8)));

#define S_WAITCNT_VMCNT(n) asm volatile("s_waitcnt vmcnt(" #n ")" ::: "memory")
__device__ __forceinline__ void wave_barrier() {
  asm volatile("" ::: "memory");
  __builtin_amdgcn_s_barrier();
  asm volatile("" ::: "memory");
}

__device__ __forceinline__ unsigned short f2bf(float f) {
  unsigned int u = __float_as_uint(f);
  u += 0x7FFFu + ((u >> 16) & 1u);
  return (unsigned short)(u >> 16);
}
__device__ __forceinline__ float bf2f(unsigned short u) {
  return __uint_as_float((unsigned int)u << 16);
}

__device__ __forceinline__ void gload_lds16(const void* g, void* l) {
  __builtin_amdgcn_global_load_lds(
      (const __attribute__((address_space(1))) unsigned int*)g,
      (__attribute__((address_space(3))) unsigned int*)l, 16, 0, 0);
}

// ---------------- fused prepass: router + Wg/Wu transpose + Wd transpose ----
// Register-only 8x4 transpose per thread, 64r x 128c tile, 256 threads.
// Lane map rg=tid&7, cg=tid>>3 makes BOTH sides coalesced:
//  - loads: lanes with equal rg (stride-8) read one row, 32 f32 = 128B chunks
//  - stores: 8 consecutive lanes (rg 0..7, cg fixed) write 64 ushorts = 128B
// (R10's tj/ti map had isolated 16B stores -> 25% write sector efficiency.)
__device__ __forceinline__ void transpose_body(const float* s,
                                               unsigned short* d,
                                               int R, int C, int r0, int c0) {
  int tid = threadIdx.x;
  int rg = tid & 7, cg = tid >> 3;          // cg 0..31
  const float* sb = s + (size_t)(r0 + rg * 8) * C + c0 + cg * 4;
  f32x4 v[8];
#pragma unroll
  for (int j = 0; j < 8; j++) v[j] = *(const f32x4*)(sb + (size_t)j * C);
  unsigned short* db = d + (size_t)(c0 + cg * 4) * R + r0 + rg * 8;
#pragma unroll
  for (int cc = 0; cc < 4; cc++) {
    ushort8 o;
#pragma unroll
    for (int j = 0; j < 8; j++) o[j] = f2bf(v[j][cc]);
    *(ushort8*)(db + (size_t)cc * R) = o;
  }
}

__global__ void prepass_kernel(const float* __restrict__ x,
                               const float* __restrict__ Wr,
                               const float* __restrict__ Wg,
                               const float* __restrict__ Wu,
                               const float* __restrict__ Wd,
                               float* __restrict__ logits,
                               unsigned short* __restrict__ xbf,
                               unsigned short* __restrict__ Wgt,
                               unsigned short* __restrict__ Wut,
                               unsigned short* __restrict__ Wdt,
                               int4* __restrict__ tokinfo,
                               int* __restrict__ cnt) {
  const int bid = blockIdx.x;
  if (bid < 1024) {
    // -------- router: 4 tokens per block, wave per token --------
    int wv = threadIdx.x >> 6, lane = threadIdx.x & 63;
    int t = bid * 4 + wv;
    const float* xr = x + (size_t)t * HD;
    unsigned short* xbr = xbf + (size_t)t * HD;
    float acc[NE];
#pragma unroll
    for (int e = 0; e < NE; e++) acc[e] = 0.f;
    for (int hi = 0; hi < HD / 256; hi++) {
      int h = hi * 256 + lane * 4;
      f32x4 xv = *(const f32x4*)(xr + h);
      ushort4 o = { f2bf(xv[0]), f2bf(xv[1]), f2bf(xv[2]), f2bf(xv[3]) };
      *(ushort4*)(xbr + h) = o;
#pragma unroll
      for (int j = 0; j < 4; j++) {
        const float4* w4 = (const float4*)(Wr + (size_t)(h + j) * NE);
        float4 a = w4[0], b = w4[1];
        float xs = xv[j];
        acc[0] += xs * a.x; acc[1] += xs * a.y; acc[2] += xs * a.z; acc[3] += xs * a.w;
        acc[4] += xs * b.x; acc[5] += xs * b.y; acc[6] += xs * b.z; acc[7] += xs * b.w;
      }
    }
#pragma unroll
    for (int m = 32; m > 0; m >>= 1) {
#pragma unroll
      for (int e = 0; e < NE; e++) acc[e] += __shfl_xor(acc[e], m, 64);
    }
    if (lane < NE) logits[(size_t)t * NE + lane] = acc[lane];
    if (lane == 0) {
      int e0 = 0;
#pragma unroll
      for (int e = 1; e < NE; e++) if (acc[e] > acc[e0]) e0 = e;
      int e1 = (e0 == 0) ? 1 : 0;
#pragma unroll
      for (int e = 0; e < NE; e++) if (e != e0 && acc[e] > acc[e1]) e1 = e;
      float ex = expf(acc[e1] - acc[e0]);   // <= 1
      float w0 = 1.f / (1.f + ex);
      float w1 = ex / (1.f + ex);
      atomicAdd(&cnt[e0], 1);
      atomicAdd(&cnt[e1], 1);
      tokinfo[t] = make_int4(e0, e1, __float_as_int(w0), __float_as_int(w1));
    }
  } else if (bid < 1024 + 5632) {
    // -------- Wg/Wu transpose: [E][HD][NI] -> [E][NI][HD] --------
    // 11 xt (128c) x 32 yt (64r) x 16 (e,sel)
    int r = bid - 1024;
    int xt = r % 11; r /= 11;
    int yt = r % 32; r /= 32;
    int e = r >> 1, sel = r & 1;
    const float* sp = (sel ? Wu : Wg) + (size_t)e * HD * NI;
    unsigned short* dp = (sel ? Wut : Wgt) + (size_t)e * HD * NI;
    transpose_body(sp, dp, HD, NI, yt * 64, xt * 128);
  } else {
    // -------- Wd transpose: [E][NI][HD] -> [E][HD][NI] --------
    // 16 xt (128c) x 22 yt (64r) x 8 e
    int r = bid - 1024 - 5632;
    int xt = r % 16; r /= 16;
    int yt = r % 22; r /= 22;
    int e = r;
    const float* sp = Wd + (size_t)e * NI * HD;
    unsigned short* dp = Wdt + (size_t)e * NI * HD;
    transpose_body(sp, dp, NI, HD, yt * 64, xt * 128);
  }
}

// Fused offsets + scatter, single block (1024 threads).
// cnt[0..7]=counts, [8..15]=offsets, [16..23]=cursors.
__global__ void route_finalize_kernel(const int4* __restrict__ tokinfo,
                                      int* __restrict__ cnt,
                                      int* __restrict__ row_tok,
                                      int2* __restrict__ tok2row) {
  if (threadIdx.x == 0) {
    int o = 0;
    for (int e = 0; e < NE; e++) { cnt[8 + e] = o; o += cnt[e]; }
  }
  __syncthreads();
  for (int t = threadIdx.x; t < T_TOK; t += 1024) {
    int4 info = tokinfo[t];
    int p0 = atomicAdd(&cnt[16 + info.x], 1);
    int r0 = cnt[8 + info.x] + p0;
    row_tok[r0] = t;
    int p1 = atomicAdd(&cnt[16 + info.y], 1);
    int r1 = cnt[8 + info.y] + p1;
    row_tok[r1] = t;
    tok2row[t] = make_int2(r0, r1);
  }
}

// ---------------- grouped GEMM 1: act = silu(x@Wg) * (x@Wu) ----------------
// 128x128 tile, BK=32, 4 waves, 16x16x32 MFMA, conflict-free XOR slots,
// static XCD swizzle expert = flat_id & 7.  ONE barrier per K-step (T3):
// depth-3 buffers allow {vmcnt(6); barrier; stage(ks+2); compute(ks)}.
// launch_bounds MUST stay (256,2): 128 acc + ~100 VGPR (R2 spill lesson).
__launch_bounds__(256, 2)
__global__ void gemm1_kernel(const unsigned short* __restrict__ xbf,
                             const unsigned short* __restrict__ Wgt,
                             const unsigned short* __restrict__ Wut,
                             unsigned short* __restrict__ act,
                             const int* __restrict__ row_tok,
                             const int* __restrict__ cnt) {
  const int f = blockIdx.x + 11 * (blockIdx.y + 32 * blockIdx.z);
  const int e = f & 7;
  const int rem = f >> 3;          // 0..351
  const int nt = rem >> 5;         // 0..10
  const int mt = rem & 31;         // 0..31
  const int c = cnt[e];
  if (mt * 128 >= c) return;
  const int off = cnt[8 + e];
  const int rowbase = off + mt * 128, rowend = off + c;
  const int i0 = nt * 128;
  __shared__ __align__(16) char smem[73728];
  const int lane = threadIdx.x & 63, w = threadIdx.x >> 6;
  const int wr = w >> 1, wc = w & 1;

  const int rr0 = w * 16 + (lane >> 2);
  const int rr1 = rr0 + 64;
  const int q0 = (lane & 3) ^ ((rr0 >> 1) & 3);
  const int q1 = (lane & 3) ^ ((rr1 >> 1) & 3);
  int g0 = rowbase + rr0; if (g0 > rowend - 1) g0 = rowend - 1;
  int g1 = rowbase + rr1; if (g1 > rowend - 1) g1 = rowend - 1;
  const size_t tokA0 = (size_t)row_tok[g0] * HD;
  const size_t tokA1 = (size_t)row_tok[g1] * HD;
  const size_t bB0 = ((size_t)e * NI + i0 + rr0) * HD;
  const size_t bB1 = ((size_t)e * NI + i0 + rr1) * HD;
  const int ldsA = w * 1024;

  f32x4 zero = {0.f, 0.f, 0.f, 0.f};
  f32x4 accg[4][4], accu[4][4];
#pragma unroll
  for (int a = 0; a < 4; a++)
#pragma unroll
    for (int b = 0; b < 4; b++) { accg[a][b] = zero; accu[a][b] = zero; }

  auto stage = [&](int buf, int ks) {
    const int k0 = ks * 32;
    char* base = smem + buf * 24576;
    gload_lds16(xbf + tokA0 + k0 + q0 * 8, base + ldsA);
    gload_lds16(xbf + tokA1 + k0 + q1 * 8, base + ldsA + 4096);
    gload_lds16(Wgt + bB0 + k0 + q0 * 8, base + 8192 + ldsA);
    gload_lds16(Wgt + bB1 + k0 + q1 * 8, base + 8192 + ldsA + 4096);
    gload_lds16(Wut + bB0 + k0 + q0 * 8, base + 16384 + ldsA);
    gload_lds16(Wut + bB1 + k0 + q1 * 8, base + 16384 + ldsA + 4096);
  };
  const int rl = lane & 15, kslot = lane >> 4;
  auto compute = [&](int buf) {
    const char* base = smem + buf * 24576;
    bf16x8 af[4], bg[4], bu[4];
#pragma unroll
    for (int mi = 0; mi < 4; mi++) {
      int r = wr * 64 + mi * 16 + rl;
      int byt = r * 64 + ((kslot ^ ((r >> 1) & 3)) << 4);
      af[mi] = *(const bf16x8*)(base + byt);
    }
#pragma unroll
    for (int ni = 0; ni < 4; ni++) {
      int r = wc * 64 + ni * 16 + rl;
      int byt = r * 64 + ((kslot ^ ((r >> 1) & 3)) << 4);
      bg[ni] = *(const bf16x8*)(base + 8192 + byt);
      bu[ni] = *(const bf16x8*)(base + 16384 + byt);
    }
#pragma unroll
    for (int mi = 0; mi < 4; mi++)
#pragma unroll
      for (int ni = 0; ni < 4; ni++) {
        accg[mi][ni] = __builtin_amdgcn_mfma_f32_16x16x32_bf16(af[mi], bg[ni], accg[mi][ni], 0, 0, 0);
        accu[mi][ni] = __builtin_amdgcn_mfma_f32_16x16x32_bf16(af[mi], bu[ni], accu[mi][ni], 0, 0, 0);
      }
  };

  stage(0, 0);
  stage(1, 1);
  const int NKS = HD / 32;
  for (int ks = 0; ks < NKS; ks++) {
    if (ks < NKS - 1) {
      S_WAITCNT_VMCNT(6);    // tile ks landed (own); <=2 younger stages fly
    } else {
      S_WAITCNT_VMCNT(0);
    }
    wave_barrier();          // all waves: tile ks ready AND compute(ks-1) done
    if (ks + 2 < NKS) stage((ks + 2) % 3, ks + 2);
    compute(ks % 3);
  }

  const int rh = lane >> 4;
#pragma unroll
  for (int mi = 0; mi < 4; mi++)
#pragma unroll
    for (int ni = 0; ni < 4; ni++)
#pragma unroll
      for (int j = 0; j < 4; j++) {
        int grow = rowbase + wr * 64 + mi * 16 + rh * 4 + j;
        if (grow < rowend) {
          int gcol = i0 + wc * 64 + ni * 16 + rl;
          float g = accg[mi][ni][j], u = accu[mi][ni][j];
          float val = g / (1.f + __expf(-g)) * u;
          act[(size_t)grow * NI + gcol] = f2bf(val);
        }
      }
}

// ---------------- grouped GEMM 2: y[row] = act[row] @ Wd  (no atomics) ------
// Same one-barrier depth-3 schedule.  LDS 3 x 16KB = 48KB, 3 blocks/CU.
__launch_bounds__(256, 3)
__global__ void gemm2_kernel(const unsigned short* __restrict__ act,
                             const unsigned short* __restrict__ Wdt,
                             unsigned short* __restrict__ y,
                             const int* __restrict__ cnt) {
  const int f = blockIdx.x + 16 * (blockIdx.y + 32 * blockIdx.z);
  const int e = f & 7;
  const int rem = f >> 3;          // 0..511
  const int nt = rem >> 5;         // 0..15
  const int mt = rem & 31;         // 0..31
  const int c = cnt[e];
  if (mt * 128 >= c) return;
  const int off = cnt[8 + e];
  const int rowbase = off + mt * 128, rowend = off + c;
  const int n0 = nt * 128;
  __shared__ __align__(16) char smem[49152];
  const int lane = threadIdx.x & 63, w = threadIdx.x >> 6;
  const int wr = w >> 1, wc = w & 1;

  const int rr0 = w * 16 + (lane >> 2);
  const int rr1 = rr0 + 64;
  const int q0 = (lane & 3) ^ ((rr0 >> 1) & 3);
  const int q1 = (lane & 3) ^ ((rr1 >> 1) & 3);
  int g0 = rowbase + rr0; if (g0 > rowend - 1) g0 = rowend - 1;
  int g1 = rowbase + rr1; if (g1 > rowend - 1) g1 = rowend - 1;
  const size_t aA0 = (size_t)g0 * NI;
  const size_t aA1 = (size_t)g1 * NI;
  const size_t bB0 = ((size_t)e * HD + n0 + rr0) * NI;
  const size_t bB1 = ((size_t)e * HD + n0 + rr1) * NI;
  const int ldsA = w * 1024;

  f32x4 zero = {0.f, 0.f, 0.f, 0.f};
  f32x4 acc[4][4];
#pragma unroll
  for (int a = 0; a < 4; a++)
#pragma unroll
    for (int b = 0; b < 4; b++) acc[a][b] = zero;

  auto stage = [&](int buf, int ks) {
    const int k0 = ks * 32;
    char* base = smem + buf * 16384;
    gload_lds16(act + aA0 + k0 + q0 * 8, base + ldsA);
    gload_lds16(act + aA1 + k0 + q1 * 8, base + ldsA + 4096);
    gload_lds16(Wdt + bB0 + k0 + q0 * 8, base + 8192 + ldsA);
    gload_lds16(Wdt + bB1 + k0 + q1 * 8, base + 8192 + ldsA + 4096);
  };
  const int rl = lane & 15, kslot = lane >> 4;
  auto compute = [&](int buf) {
    const char* base = smem + buf * 16384;
    bf16x8 af[4], bf[4];
#pragma unroll
    for (int mi = 0; mi < 4; mi++) {
      int r = wr * 64 + mi * 16 + rl;
      int byt = r * 64 + ((kslot ^ ((r >> 1) & 3)) << 4);
      af[mi] = *(const bf16x8*)(base + byt);
    }
#pragma unroll
    for (int ni = 0; ni < 4; ni++) {
      int r = wc * 64 + ni * 16 + rl;
      int byt = r * 64 + ((kslot ^ ((r >> 1) & 3)) << 4);
      bf[ni] = *(const bf16x8*)(base + 8192 + byt);
    }
#pragma unroll
    for (int mi = 0; mi < 4; mi++)
#pragma unroll
      for (int ni = 0; ni < 4; ni++)
        acc[mi][ni] = __builtin_amdgcn_mfma_f32_16x16x32_bf16(af[mi], bf[ni], acc[mi][ni], 0, 0, 0);
  };

  stage(0, 0);
  stage(1, 1);
  const int NKS = NI / 32;
  for (int ks = 0; ks < NKS; ks++) {
    if (ks < NKS - 1) {
      S_WAITCNT_VMCNT(4);
    } else {
      S_WAITCNT_VMCNT(0);
    }
    wave_barrier();
    if (ks + 2 < NKS) stage((ks + 2) % 3, ks + 2);
    compute(ks % 3);
  }

  const int rh = lane >> 4;
#pragma unroll
  for (int mi = 0; mi < 4; mi++)
#pragma unroll
    for (int ni = 0; ni < 4; ni++)
#pragma unroll
      for (int j = 0; j < 4; j++) {
        int grow = rowbase + wr * 64 + mi * 16 + rh * 4 + j;
        if (grow < rowend) {
          int gcol = n0 + wc * 64 + ni * 16 + rl;
          y[(size_t)grow * HD + gcol] = f2bf(acc[mi][ni][j]);
        }
      }
}

// ---------------- combine: out[t] = w0*y[r0] + w1*y[r1] ----------------
__global__ void combine_kernel(const unsigned short* __restrict__ y,
                               const int2* __restrict__ tok2row,
                               const int4* __restrict__ tokinfo,
                               float* __restrict__ out) {
  int t = blockIdx.x, tid = threadIdx.x;
  int2 rr = tok2row[t];
  int4 info = tokinfo[t];
  float w0 = __int_as_float(info.z), w1 = __int_as_float(info.w);
  ushort8 a = ((const ushort8*)(y + (size_t)rr.x * HD))[tid];
  ushort8 b = ((const ushort8*)(y + (size_t)rr.y * HD))[tid];
  float4 o0, o1;
  o0.x = w0 * bf2f(a[0]) + w1 * bf2f(b[0]);
  o0.y = w0 * bf2f(a[1]) + w1 * bf2f(b[1]);
  o0.z = w0 * bf2f(a[2]) + w1 * bf2f(b[2]);
  o0.w = w0 * bf2f(a[3]) + w1 * bf2f(b[3]);
  o1.x = w0 * bf2f(a[4]) + w1 * bf2f(b[4]);
  o1.y = w0 * bf2f(a[5]) + w1 * bf2f(b[5]);
  o1.z = w0 * bf2f(a[6]) + w1 * bf2f(b[6]);
  o1.w = w0 * bf2f(a[7]) + w1 * bf2f(b[7]);
  float4* op = (float4*)(out + (size_t)t * HD + tid * 8);
  op[0] = o0; op[1] = o1;
}

// ---------------- launch ----------------
extern "C" void kernel_launch(void* const* d_in, const int* in_sizes, int n_in,
                              void* d_out, int out_size, void* d_ws, size_t ws_size,
                              hipStream_t stream) {
  const float* x  = (const float*)d_in[0];
  const float* Wr = (const float*)d_in[1];
  const float* Wg = (const float*)d_in[2];
  const float* Wu = (const float*)d_in[3];
  const float* Wd = (const float*)d_in[4];
  float* out = (float*)d_out;
  char* ws = (char*)d_ws;

  // ws layout (bytes)
  unsigned short* xbf = (unsigned short*)(ws);                 // 16,777,216
  unsigned short* Wgt = (unsigned short*)(ws + 16777216);      // 46,137,344
  unsigned short* Wut = (unsigned short*)(ws + 62914560);      // 46,137,344
  unsigned short* Wdt = (unsigned short*)(ws + 109051904);     // 46,137,344
  unsigned short* act = (unsigned short*)(ws + 155189248);     // 23,068,672
  // y aliases Wgt: gemm1 (last reader of Wgt) completes before gemm2 writes y.
  unsigned short* yb  = (unsigned short*)(ws + 16777216);      // 33,554,432
  int4*  tokinfo      = (int4*)(ws + 178257920);               // 65,536
  int*   row_tok      = (int*)(ws + 178323456);                // 32,768
  int2*  tok2row      = (int2*)(ws + 178356224);               // 32,768
  int*   cnt          = (int*)(ws + 178388992);                // 128

  hipMemsetAsync(cnt, 0, 128, stream);

  // router (1024) + Wg/Wu transpose (5632) + Wd transpose (2816), one launch
  prepass_kernel<<<1024 + 5632 + 2816, 256, 0, stream>>>(
      x, Wr, Wg, Wu, Wd, out + (size_t)T_TOK * HD, xbf, Wgt, Wut, Wdt,
      tokinfo, cnt);
  route_finalize_kernel<<<1, 1024, 0, stream>>>(tokinfo, cnt, row_tok, tok2row);

  gemm1_kernel<<<dim3(11, 32, NE), 256, 0, stream>>>(xbf, Wgt, Wut, act, row_tok, cnt);
  gemm2_kernel<<<dim3(16, 32, NE), 256, 0, stream>>>(act, Wdt, yb, cnt);
  combine_kernel<<<T_TOK, 256, 0, stream>>>(yb, tok2row, tokinfo, out);
}

// Round 12
// 435.355 us; speedup vs baseline: 1.0548x; 1.0548x over previous
//
#include <hip/hip_runtime.h>

#define T_TOK 4096
#define HD 2048
#define NE 8
#define NI 1408

typedef __bf16 bf16x8 __attribute__((ext_vector_type(8)));
typedef float f32x4 __attribute__((ext_vector_type(4)));
typedef unsigned short ushort8 __attribute__((ext_vector_type(8)));

#define S_WAITCNT_VMCNT(n) asm volatile("s_waitcnt vmcnt(" #n ")" ::: "memory")
__device__ __forceinline__ void wave_barrier() {
  asm volatile("" ::: "memory");
  __builtin_amdgcn_s_barrier();
  asm volatile("" ::: "memory");
}

__device__ __forceinline__ unsigned short f2bf(float f) {
  unsigned int u = __float_as_uint(f);
  u += 0x7FFFu + ((u >> 16) & 1u);
  return (unsigned short)(u >> 16);
}
__device__ __forceinline__ float bf2f(unsigned short u) {
  return __uint_as_float((unsigned int)u << 16);
}

__device__ __forceinline__ void gload_lds16(const void* g, void* l) {
  __builtin_amdgcn_global_load_lds(
      (const __attribute__((address_space(1))) unsigned int*)g,
      (__attribute__((address_space(3))) unsigned int*)l, 16, 0, 0);
}

// Register-only 8x4 transpose per thread, 64r x 128c tile, 256 threads.
// Both sides 128B-coalesced (R11 verified: sector efficiency is not the
// prepass limiter; keep this shape).
__device__ __forceinline__ void transpose_body(const float* s,
                                               unsigned short* d,
                                               int R, int C, int r0, int c0) {
  int tid = threadIdx.x;
  int rg = tid & 7, cg = tid >> 3;          // cg 0..31
  const float* sb = s + (size_t)(r0 + rg * 8) * C + c0 + cg * 4;
  f32x4 v[8];
#pragma unroll
  for (int j = 0; j < 8; j++) v[j] = *(const f32x4*)(sb + (size_t)j * C);
  unsigned short* db = d + (size_t)(c0 + cg * 4) * R + r0 + rg * 8;
#pragma unroll
  for (int cc = 0; cc < 4; cc++) {
    ushort8 o;
#pragma unroll
    for (int j = 0; j < 8; j++) o[j] = f2bf(v[j][cc]);
    *(ushort8*)(db + (size_t)cc * R) = o;
  }
}

// ---------------- prepass: router + Wg/Wu transpose (Wd moved into gemm1) ---
__global__ void prepass_kernel(const float* __restrict__ x,
                               const float* __restrict__ Wr,
                               const float* __restrict__ Wg,
                               const float* __restrict__ Wu,
                               float* __restrict__ logits,
                               unsigned short* __restrict__ xbf,
                               unsigned short* __restrict__ Wgt,
                               unsigned short* __restrict__ Wut,
                               int4* __restrict__ tokinfo,
                               int* __restrict__ cnt) {
  const int bid = blockIdx.x;
  if (bid < 1024) {
    // -------- router: 4 tokens per block, wave per token --------
    int wv = threadIdx.x >> 6, lane = threadIdx.x & 63;
    int t = bid * 4 + wv;
    const float* xr = x + (size_t)t * HD;
    unsigned short* xbr = xbf + (size_t)t * HD;
    float acc[NE];
#pragma unroll
    for (int e = 0; e < NE; e++) acc[e] = 0.f;
    for (int hi = 0; hi < HD / 256; hi++) {
      int h = hi * 256 + lane * 4;
      f32x4 xv = *(const f32x4*)(xr + h);
      ushort4 o = { f2bf(xv[0]), f2bf(xv[1]), f2bf(xv[2]), f2bf(xv[3]) };
      *(ushort4*)(xbr + h) = o;
#pragma unroll
      for (int j = 0; j < 4; j++) {
        const float4* w4 = (const float4*)(Wr + (size_t)(h + j) * NE);
        float4 a = w4[0], b = w4[1];
        float xs = xv[j];
        acc[0] += xs * a.x; acc[1] += xs * a.y; acc[2] += xs * a.z; acc[3] += xs * a.w;
        acc[4] += xs * b.x; acc[5] += xs * b.y; acc[6] += xs * b.z; acc[7] += xs * b.w;
      }
    }
#pragma unroll
    for (int m = 32; m > 0; m >>= 1) {
#pragma unroll
      for (int e = 0; e < NE; e++) acc[e] += __shfl_xor(acc[e], m, 64);
    }
    if (lane < NE) logits[(size_t)t * NE + lane] = acc[lane];
    if (lane == 0) {
      int e0 = 0;
#pragma unroll
      for (int e = 1; e < NE; e++) if (acc[e] > acc[e0]) e0 = e;
      int e1 = (e0 == 0) ? 1 : 0;
#pragma unroll
      for (int e = 0; e < NE; e++) if (e != e0 && acc[e] > acc[e1]) e1 = e;
      float ex = expf(acc[e1] - acc[e0]);   // <= 1
      float w0 = 1.f / (1.f + ex);
      float w1 = ex / (1.f + ex);
      atomicAdd(&cnt[e0], 1);
      atomicAdd(&cnt[e1], 1);
      tokinfo[t] = make_int4(e0, e1, __float_as_int(w0), __float_as_int(w1));
    }
  } else {
    // -------- Wg/Wu transpose: [E][HD][NI] -> [E][NI][HD] --------
    // 11 xt (128c) x 32 yt (64r) x 16 (e,sel)
    int r = bid - 1024;
    int xt = r % 11; r /= 11;
    int yt = r % 32; r /= 32;
    int e = r >> 1, sel = r & 1;
    const float* sp = (sel ? Wu : Wg) + (size_t)e * HD * NI;
    unsigned short* dp = (sel ? Wut : Wgt) + (size_t)e * HD * NI;
    transpose_body(sp, dp, HD, NI, yt * 64, xt * 128);
  }
}

// Fused offsets + scatter, single block (1024 threads).
// cnt[0..7]=counts, [8..15]=offsets, [16..23]=cursors.
__global__ void route_finalize_kernel(const int4* __restrict__ tokinfo,
                                      int* __restrict__ cnt,
                                      int* __restrict__ row_tok,
                                      int2* __restrict__ tok2row) {
  if (threadIdx.x == 0) {
    int o = 0;
    for (int e = 0; e < NE; e++) { cnt[8 + e] = o; o += cnt[e]; }
  }
  __syncthreads();
  for (int t = threadIdx.x; t < T_TOK; t += 1024) {
    int4 info = tokinfo[t];
    int p0 = atomicAdd(&cnt[16 + info.x], 1);
    int r0 = cnt[8 + info.x] + p0;
    row_tok[r0] = t;
    int p1 = atomicAdd(&cnt[16 + info.y], 1);
    int r1 = cnt[8 + info.y] + p1;
    row_tok[r1] = t;
    tok2row[t] = make_int2(r0, r1);
  }
}

// ---------------- grouped GEMM 1 (+ Wd transpose in spare blocks) ----------
// 128x128 tile, BK=32, 4 waves, 16x16x32 MFMA, conflict-free XOR slots,
// one barrier per K-step, depth-3 counted-vmcnt pipeline.
// Grid dim3(11,32,16): F = x+11*(y+32*z); e = F&7 (XCD affinity for BOTH
// parts); r = F>>3: r<352 -> gemm tile (nt=r>>5, mt=r&31); r>=352 -> one
// 64x128 Wd transpose tile (needed only by gemm2, so it rides in gemm1's
// grid holes: 2112 empty gemm blocks + BW headroom absorb it).
// launch_bounds MUST stay (256,2): 128 acc + ~100 VGPR (R2 spill lesson).
__launch_bounds__(256, 2)
__global__ void gemm1_kernel(const unsigned short* __restrict__ xbf,
                             const unsigned short* __restrict__ Wgt,
                             const unsigned short* __restrict__ Wut,
                             const float* __restrict__ Wd,
                             unsigned short* __restrict__ Wdt,
                             unsigned short* __restrict__ act,
                             const int* __restrict__ row_tok,
                             const int* __restrict__ cnt) {
  const int F = blockIdx.x + 11 * (blockIdx.y + 32 * blockIdx.z);
  const int e = F & 7;
  const int r = F >> 3;            // 0..703
  if (r >= 352) {
    // Wd transpose: [E][NI][HD] -> [E][HD][NI]; 16 xt (128c) x 22 yt (64r)
    const int t = r - 352;
    const int xt = t & 15, yt = t >> 4;
    transpose_body(Wd + (size_t)e * NI * HD, Wdt + (size_t)e * NI * HD,
                   NI, HD, yt * 64, xt * 128);
    return;
  }
  const int nt = r >> 5;           // 0..10
  const int mt = r & 31;           // 0..31
  const int c = cnt[e];
  if (mt * 128 >= c) return;
  const int off = cnt[8 + e];
  const int rowbase = off + mt * 128, rowend = off + c;
  const int i0 = nt * 128;
  __shared__ __align__(16) char smem[73728];
  const int lane = threadIdx.x & 63, w = threadIdx.x >> 6;
  const int wr = w >> 1, wc = w & 1;

  const int rr0 = w * 16 + (lane >> 2);
  const int rr1 = rr0 + 64;
  const int q0 = (lane & 3) ^ ((rr0 >> 1) & 3);
  const int q1 = (lane & 3) ^ ((rr1 >> 1) & 3);
  int g0 = rowbase + rr0; if (g0 > rowend - 1) g0 = rowend - 1;
  int g1 = rowbase + rr1; if (g1 > rowend - 1) g1 = rowend - 1;
  const size_t tokA0 = (size_t)row_tok[g0] * HD;
  const size_t tokA1 = (size_t)row_tok[g1] * HD;
  const size_t bB0 = ((size_t)e * NI + i0 + rr0) * HD;
  const size_t bB1 = ((size_t)e * NI + i0 + rr1) * HD;
  const int ldsA = w * 1024;

  f32x4 zero = {0.f, 0.f, 0.f, 0.f};
  f32x4 accg[4][4], accu[4][4];
#pragma unroll
  for (int a = 0; a < 4; a++)
#pragma unroll
    for (int b = 0; b < 4; b++) { accg[a][b] = zero; accu[a][b] = zero; }

  auto stage = [&](int buf, int ks) {
    const int k0 = ks * 32;
    char* base = smem + buf * 24576;
    gload_lds16(xbf + tokA0 + k0 + q0 * 8, base + ldsA);
    gload_lds16(xbf + tokA1 + k0 + q1 * 8, base + ldsA + 4096);
    gload_lds16(Wgt + bB0 + k0 + q0 * 8, base + 8192 + ldsA);
    gload_lds16(Wgt + bB1 + k0 + q1 * 8, base + 8192 + ldsA + 4096);
    gload_lds16(Wut + bB0 + k0 + q0 * 8, base + 16384 + ldsA);
    gload_lds16(Wut + bB1 + k0 + q1 * 8, base + 16384 + ldsA + 4096);
  };
  const int rl = lane & 15, kslot = lane >> 4;
  auto compute = [&](int buf) {
    const char* base = smem + buf * 24576;
    bf16x8 af[4], bg[4], bu[4];
#pragma unroll
    for (int mi = 0; mi < 4; mi++) {
      int rr = wr * 64 + mi * 16 + rl;
      int byt = rr * 64 + ((kslot ^ ((rr >> 1) & 3)) << 4);
      af[mi] = *(const bf16x8*)(base + byt);
    }
#pragma unroll
    for (int ni = 0; ni < 4; ni++) {
      int rr = wc * 64 + ni * 16 + rl;
      int byt = rr * 64 + ((kslot ^ ((rr >> 1) & 3)) << 4);
      bg[ni] = *(const bf16x8*)(base + 8192 + byt);
      bu[ni] = *(const bf16x8*)(base + 16384 + byt);
    }
#pragma unroll
    for (int mi = 0; mi < 4; mi++)
#pragma unroll
      for (int ni = 0; ni < 4; ni++) {
        accg[mi][ni] = __builtin_amdgcn_mfma_f32_16x16x32_bf16(af[mi], bg[ni], accg[mi][ni], 0, 0, 0);
        accu[mi][ni] = __builtin_amdgcn_mfma_f32_16x16x32_bf16(af[mi], bu[ni], accu[mi][ni], 0, 0, 0);
      }
  };

  stage(0, 0);
  stage(1, 1);
  const int NKS = HD / 32;
  for (int ks = 0; ks < NKS; ks++) {
    if (ks < NKS - 1) {
      S_WAITCNT_VMCNT(6);    // tile ks landed (own); <=2 younger stages fly
    } else {
      S_WAITCNT_VMCNT(0);
    }
    wave_barrier();          // all waves: tile ks ready AND compute(ks-1) done
    if (ks + 2 < NKS) stage((ks + 2) % 3, ks + 2);
    compute(ks % 3);
  }

  const int rh = lane >> 4;
#pragma unroll
  for (int mi = 0; mi < 4; mi++)
#pragma unroll
    for (int ni = 0; ni < 4; ni++)
#pragma unroll
      for (int j = 0; j < 4; j++) {
        int grow = rowbase + wr * 64 + mi * 16 + rh * 4 + j;
        if (grow < rowend) {
          int gcol = i0 + wc * 64 + ni * 16 + rl;
          float g = accg[mi][ni][j], u = accu[mi][ni][j];
          float val = g / (1.f + __expf(-g)) * u;
          act[(size_t)grow * NI + gcol] = f2bf(val);
        }
      }
}

// ---------------- grouped GEMM 2: y[row] = act[row] @ Wd  (no atomics) ------
// Same one-barrier depth-3 schedule.  LDS 3 x 16KB = 48KB, 3 blocks/CU.
__launch_bounds__(256, 3)
__global__ void gemm2_kernel(const unsigned short* __restrict__ act,
                             const unsigned short* __restrict__ Wdt,
                             unsigned short* __restrict__ y,
                             const int* __restrict__ cnt) {
  const int f = blockIdx.x + 16 * (blockIdx.y + 32 * blockIdx.z);
  const int e = f & 7;
  const int rem = f >> 3;          // 0..511
  const int nt = rem >> 5;         // 0..15
  const int mt = rem & 31;         // 0..31
  const int c = cnt[e];
  if (mt * 128 >= c) return;
  const int off = cnt[8 + e];
  const int rowbase = off + mt * 128, rowend = off + c;
  const int n0 = nt * 128;
  __shared__ __align__(16) char smem[49152];
  const int lane = threadIdx.x & 63, w = threadIdx.x >> 6;
  const int wr = w >> 1, wc = w & 1;

  const int rr0 = w * 16 + (lane >> 2);
  const int rr1 = rr0 + 64;
  const int q0 = (lane & 3) ^ ((rr0 >> 1) & 3);
  const int q1 = (lane & 3) ^ ((rr1 >> 1) & 3);
  int g0 = rowbase + rr0; if (g0 > rowend - 1) g0 = rowend - 1;
  int g1 = rowbase + rr1; if (g1 > rowend - 1) g1 = rowend - 1;
  const size_t aA0 = (size_t)g0 * NI;
  const size_t aA1 = (size_t)g1 * NI;
  const size_t bB0 = ((size_t)e * HD + n0 + rr0) * NI;
  const size_t bB1 = ((size_t)e * HD + n0 + rr1) * NI;
  const int ldsA = w * 1024;

  f32x4 zero = {0.f, 0.f, 0.f, 0.f};
  f32x4 acc[4][4];
#pragma unroll
  for (int a = 0; a < 4; a++)
#pragma unroll
    for (int b = 0; b < 4; b++) acc[a][b] = zero;

  auto stage = [&](int buf, int ks) {
    const int k0 = ks * 32;
    char* base = smem + buf * 16384;
    gload_lds16(act + aA0 + k0 + q0 * 8, base + ldsA);
    gload_lds16(act + aA1 + k0 + q1 * 8, base + ldsA + 4096);
    gload_lds16(Wdt + bB0 + k0 + q0 * 8, base + 8192 + ldsA);
    gload_lds16(Wdt + bB1 + k0 + q1 * 8, base + 8192 + ldsA + 4096);
  };
  const int rl = lane & 15, kslot = lane >> 4;
  auto compute = [&](int buf) {
    const char* base = smem + buf * 16384;
    bf16x8 af[4], bf[4];
#pragma unroll
    for (int mi = 0; mi < 4; mi++) {
      int rr = wr * 64 + mi * 16 + rl;
      int byt = rr * 64 + ((kslot ^ ((rr >> 1) & 3)) << 4);
      af[mi] = *(const bf16x8*)(base + byt);
    }
#pragma unroll
    for (int ni = 0; ni < 4; ni++) {
      int rr = wc * 64 + ni * 16 + rl;
      int byt = rr * 64 + ((kslot ^ ((rr >> 1) & 3)) << 4);
      bf[ni] = *(const bf16x8*)(base + 8192 + byt);
    }
#pragma unroll
    for (int mi = 0; mi < 4; mi++)
#pragma unroll
      for (int ni = 0; ni < 4; ni++)
        acc[mi][ni] = __builtin_amdgcn_mfma_f32_16x16x32_bf16(af[mi], bf[ni], acc[mi][ni], 0, 0, 0);
  };

  stage(0, 0);
  stage(1, 1);
  const int NKS = NI / 32;
  for (int ks = 0; ks < NKS; ks++) {
    if (ks < NKS - 1) {
      S_WAITCNT_VMCNT(4);
    } else {
      S_WAITCNT_VMCNT(0);
    }
    wave_barrier();
    if (ks + 2 < NKS) stage((ks + 2) % 3, ks + 2);
    compute(ks % 3);
  }

  const int rh = lane >> 4;
#pragma unroll
  for (int mi = 0; mi < 4; mi++)
#pragma unroll
    for (int ni = 0; ni < 4; ni++)
#pragma unroll
      for (int j = 0; j < 4; j++) {
        int grow = rowbase + wr * 64 + mi * 16 + rh * 4 + j;
        if (grow < rowend) {
          int gcol = n0 + wc * 64 + ni * 16 + rl;
          y[(size_t)grow * HD + gcol] = f2bf(acc[mi][ni][j]);
        }
      }
}

// ---------------- combine: out[t] = w0*y[r0] + w1*y[r1] ----------------
__global__ void combine_kernel(const unsigned short* __restrict__ y,
                               const int2* __restrict__ tok2row,
                               const int4* __restrict__ tokinfo,
                               float* __restrict__ out) {
  int t = blockIdx.x, tid = threadIdx.x;
  int2 rr = tok2row[t];
  int4 info = tokinfo[t];
  float w0 = __int_as_float(info.z), w1 = __int_as_float(info.w);
  ushort8 a = ((const ushort8*)(y + (size_t)rr.x * HD))[tid];
  ushort8 b = ((const ushort8*)(y + (size_t)rr.y * HD))[tid];
  float4 o0, o1;
  o0.x = w0 * bf2f(a[0]) + w1 * bf2f(b[0]);
  o0.y = w0 * bf2f(a[1]) + w1 * bf2f(b[1]);
  o0.z = w0 * bf2f(a[2]) + w1 * bf2f(b[2]);
  o0.w = w0 * bf2f(a[3]) + w1 * bf2f(b[3]);
  o1.x = w0 * bf2f(a[4]) + w1 * bf2f(b[4]);
  o1.y = w0 * bf2f(a[5]) + w1 * bf2f(b[5]);
  o1.z = w0 * bf2f(a[6]) + w1 * bf2f(b[6]);
  o1.w = w0 * bf2f(a[7]) + w1 * bf2f(b[7]);
  float4* op = (float4*)(out + (size_t)t * HD + tid * 8);
  op[0] = o0; op[1] = o1;
}

// ---------------- launch ----------------
extern "C" void kernel_launch(void* const* d_in, const int* in_sizes, int n_in,
                              void* d_out, int out_size, void* d_ws, size_t ws_size,
                              hipStream_t stream) {
  const float* x  = (const float*)d_in[0];
  const float* Wr = (const float*)d_in[1];
  const float* Wg = (const float*)d_in[2];
  const float* Wu = (const float*)d_in[3];
  const float* Wd = (const float*)d_in[4];
  float* out = (float*)d_out;
  char* ws = (char*)d_ws;

  // ws layout (bytes)
  unsigned short* xbf = (unsigned short*)(ws);                 // 16,777,216
  unsigned short* Wgt = (unsigned short*)(ws + 16777216);      // 46,137,344
  unsigned short* Wut = (unsigned short*)(ws + 62914560);      // 46,137,344
  unsigned short* Wdt = (unsigned short*)(ws + 109051904);     // 46,137,344
  unsigned short* act = (unsigned short*)(ws + 155189248);     // 23,068,672
  // y aliases Wgt: gemm1 (last reader of Wgt) completes before gemm2 writes y.
  unsigned short* yb  = (unsigned short*)(ws + 16777216);      // 33,554,432
  int4*  tokinfo      = (int4*)(ws + 178257920);               // 65,536
  int*   row_tok      = (int*)(ws + 178323456);                // 32,768
  int2*  tok2row      = (int2*)(ws + 178356224);               // 32,768
  int*   cnt          = (int*)(ws + 178388992);                // 128

  hipMemsetAsync(cnt, 0, 128, stream);

  // router (1024) + Wg/Wu transpose (5632); Wd transpose rides in gemm1.
  prepass_kernel<<<1024 + 5632, 256, 0, stream>>>(
      x, Wr, Wg, Wu, out + (size_t)T_TOK * HD, xbf, Wgt, Wut, tokinfo, cnt);
  route_finalize_kernel<<<1, 1024, 0, stream>>>(tokinfo, cnt, row_tok, tok2row);

  gemm1_kernel<<<dim3(11, 32, 16), 256, 0, stream>>>(
      xbf, Wgt, Wut, Wd, Wdt, act, row_tok, cnt);
  gemm2_kernel<<<dim3(16, 32, NE), 256, 0, stream>>>(act, Wdt, yb, cnt);
  combine_kernel<<<T_TOK, 256, 0, stream>>>(yb, tok2row, tokinfo, out);
}

// Round 13
// 422.963 us; speedup vs baseline: 1.0857x; 1.0293x over previous
//
#include <hip/hip_runtime.h>

#define T_TOK 4096
#define HD 2048
#define NE 8
#define NI 1408

typedef __bf16 bf16x8 __attribute__((ext_vector_type(8)));
typedef float f32x4 __attribute__((ext_vector_type(4)));
typedef unsigned short ushort8 __attribute__((ext_vector_type(8)));

#define S_WAITCNT_VMCNT(n) asm volatile("s_waitcnt vmcnt(" #n ")" ::: "memory")
__device__ __forceinline__ void wave_barrier() {
  asm volatile("" ::: "memory");
  __builtin_amdgcn_s_barrier();
  asm volatile("" ::: "memory");
}

__device__ __forceinline__ unsigned short f2bf(float f) {
  unsigned int u = __float_as_uint(f);
  u += 0x7FFFu + ((u >> 16) & 1u);
  return (unsigned short)(u >> 16);
}
__device__ __forceinline__ float bf2f(unsigned short u) {
  return __uint_as_float((unsigned int)u << 16);
}

__device__ __forceinline__ void gload_lds16(const void* g, void* l) {
  __builtin_amdgcn_global_load_lds(
      (const __attribute__((address_space(1))) unsigned int*)g,
      (__attribute__((address_space(3))) unsigned int*)l, 16, 0, 0);
}

// Register-only 8x4 transpose per thread, 64r x 128c tile, 256 threads.
// Non-temporal on both sides: src f32 is read-once, dst bf16 is write-once —
// keep them out of L2/L3 (pollution theory, R13).
__device__ __forceinline__ void transpose_body_nt(const float* s,
                                                  unsigned short* d,
                                                  int R, int C, int r0, int c0) {
  int tid = threadIdx.x;
  int rg = tid & 7, cg = tid >> 3;          // cg 0..31
  const float* sb = s + (size_t)(r0 + rg * 8) * C + c0 + cg * 4;
  f32x4 v[8];
#pragma unroll
  for (int j = 0; j < 8; j++)
    v[j] = __builtin_nontemporal_load((const f32x4*)(sb + (size_t)j * C));
  unsigned short* db = d + (size_t)(c0 + cg * 4) * R + r0 + rg * 8;
#pragma unroll
  for (int cc = 0; cc < 4; cc++) {
    ushort8 o;
#pragma unroll
    for (int j = 0; j < 8; j++) o[j] = f2bf(v[j][cc]);
    __builtin_nontemporal_store(o, (ushort8*)(db + (size_t)cc * R));
  }
}

// ---------------- prepass: router + Wg/Wu transpose (Wd rides in gemm1) ----
// Transpose blocks keep one 128-col range and WALK 8 consecutive 64-row
// tiles (write page locality: each 4KB column line gets 8 nearby-in-time
// 128B chunks instead of one).  Grid: 1024 router + 11x4x16 = 704 walk
// blocks.
__global__ void prepass_kernel(const float* __restrict__ x,
                               const float* __restrict__ Wr,
                               const float* __restrict__ Wg,
                               const float* __restrict__ Wu,
                               float* __restrict__ logits,
                               unsigned short* __restrict__ xbf,
                               unsigned short* __restrict__ Wgt,
                               unsigned short* __restrict__ Wut,
                               int4* __restrict__ tokinfo,
                               int* __restrict__ cnt) {
  const int bid = blockIdx.x;
  if (bid < 1024) {
    // -------- router: 4 tokens per block, wave per token --------
    int wv = threadIdx.x >> 6, lane = threadIdx.x & 63;
    int t = bid * 4 + wv;
    const float* xr = x + (size_t)t * HD;
    unsigned short* xbr = xbf + (size_t)t * HD;
    float acc[NE];
#pragma unroll
    for (int e = 0; e < NE; e++) acc[e] = 0.f;
    for (int hi = 0; hi < HD / 256; hi++) {
      int h = hi * 256 + lane * 4;
      f32x4 xv = __builtin_nontemporal_load((const f32x4*)(xr + h));
      ushort4 o = { f2bf(xv[0]), f2bf(xv[1]), f2bf(xv[2]), f2bf(xv[3]) };
      *(ushort4*)(xbr + h) = o;
#pragma unroll
      for (int j = 0; j < 4; j++) {
        const float4* w4 = (const float4*)(Wr + (size_t)(h + j) * NE);
        float4 a = w4[0], b = w4[1];
        float xs = xv[j];
        acc[0] += xs * a.x; acc[1] += xs * a.y; acc[2] += xs * a.z; acc[3] += xs * a.w;
        acc[4] += xs * b.x; acc[5] += xs * b.y; acc[6] += xs * b.z; acc[7] += xs * b.w;
      }
    }
#pragma unroll
    for (int m = 32; m > 0; m >>= 1) {
#pragma unroll
      for (int e = 0; e < NE; e++) acc[e] += __shfl_xor(acc[e], m, 64);
    }
    if (lane < NE) logits[(size_t)t * NE + lane] = acc[lane];
    if (lane == 0) {
      int e0 = 0;
#pragma unroll
      for (int e = 1; e < NE; e++) if (acc[e] > acc[e0]) e0 = e;
      int e1 = (e0 == 0) ? 1 : 0;
#pragma unroll
      for (int e = 0; e < NE; e++) if (e != e0 && acc[e] > acc[e1]) e1 = e;
      float ex = expf(acc[e1] - acc[e0]);   // <= 1
      float w0 = 1.f / (1.f + ex);
      float w1 = ex / (1.f + ex);
      atomicAdd(&cnt[e0], 1);
      atomicAdd(&cnt[e1], 1);
      tokinfo[t] = make_int4(e0, e1, __float_as_int(w0), __float_as_int(w1));
    }
  } else {
    // -------- Wg/Wu transpose: [E][HD][NI] -> [E][NI][HD] --------
    int q = bid - 1024;            // 0..703
    int xt = q % 11; q /= 11;      // col tile (128c)
    int rs = q & 3;  q >>= 2;      // row segment (8 x 64r)
    int e = q >> 1, sel = q & 1;
    const float* sp = (sel ? Wu : Wg) + (size_t)e * HD * NI;
    unsigned short* dp = (sel ? Wut : Wgt) + (size_t)e * HD * NI;
#pragma unroll
    for (int rt = 0; rt < 8; rt++)
      transpose_body_nt(sp, dp, HD, NI, (rs * 8 + rt) * 64, xt * 128);
  }
}

// Fused offsets + scatter, single block (1024 threads).
// cnt[0..7]=counts, [8..15]=offsets, [16..23]=cursors.
__global__ void route_finalize_kernel(const int4* __restrict__ tokinfo,
                                      int* __restrict__ cnt,
                                      int* __restrict__ row_tok,
                                      int2* __restrict__ tok2row) {
  if (threadIdx.x == 0) {
    int o = 0;
    for (int e = 0; e < NE; e++) { cnt[8 + e] = o; o += cnt[e]; }
  }
  __syncthreads();
  for (int t = threadIdx.x; t < T_TOK; t += 1024) {
    int4 info = tokinfo[t];
    int p0 = atomicAdd(&cnt[16 + info.x], 1);
    int r0 = cnt[8 + info.x] + p0;
    row_tok[r0] = t;
    int p1 = atomicAdd(&cnt[16 + info.y], 1);
    int r1 = cnt[8 + info.y] + p1;
    row_tok[r1] = t;
    tok2row[t] = make_int2(r0, r1);
  }
}

// ---------------- grouped GEMM 1 (+ Wd transpose in spare blocks) ----------
// 128x128 tile, BK=32, 4 waves, 16x16x32 MFMA, conflict-free XOR slots,
// one barrier per K-step, depth-3 counted-vmcnt pipeline.
// Grid dim3(11,32,16): F = x+11*(y+32*z); e = F&7; r = F>>3: r<352 -> gemm
// tile; r>=352 -> one 64x128 Wd transpose tile (yt-fastest decode so
// consecutive blocks walk rows of one col-panel; nt load/store).
// launch_bounds MUST stay (256,2): 128 acc + ~100 VGPR (R2 spill lesson).
__launch_bounds__(256, 2)
__global__ void gemm1_kernel(const unsigned short* __restrict__ xbf,
                             const unsigned short* __restrict__ Wgt,
                             const unsigned short* __restrict__ Wut,
                             const float* __restrict__ Wd,
                             unsigned short* __restrict__ Wdt,
                             unsigned short* __restrict__ act,
                             const int* __restrict__ row_tok,
                             const int* __restrict__ cnt) {
  const int F = blockIdx.x + 11 * (blockIdx.y + 32 * blockIdx.z);
  const int e = F & 7;
  const int r = F >> 3;            // 0..703
  if (r >= 352) {
    // Wd transpose: [E][NI][HD] -> [E][HD][NI]; 16 xt (128c) x 22 yt (64r)
    const int t = r - 352;
    const int xt = t / 22, yt = t % 22;
    transpose_body_nt(Wd + (size_t)e * NI * HD, Wdt + (size_t)e * NI * HD,
                      NI, HD, yt * 64, xt * 128);
    return;
  }
  const int nt = r >> 5;           // 0..10
  const int mt = r & 31;           // 0..31
  const int c = cnt[e];
  if (mt * 128 >= c) return;
  const int off = cnt[8 + e];
  const int rowbase = off + mt * 128, rowend = off + c;
  const int i0 = nt * 128;
  __shared__ __align__(16) char smem[73728];
  const int lane = threadIdx.x & 63, w = threadIdx.x >> 6;
  const int wr = w >> 1, wc = w & 1;

  const int rr0 = w * 16 + (lane >> 2);
  const int rr1 = rr0 + 64;
  const int q0 = (lane & 3) ^ ((rr0 >> 1) & 3);
  const int q1 = (lane & 3) ^ ((rr1 >> 1) & 3);
  int g0 = rowbase + rr0; if (g0 > rowend - 1) g0 = rowend - 1;
  int g1 = rowbase + rr1; if (g1 > rowend - 1) g1 = rowend - 1;
  const size_t tokA0 = (size_t)row_tok[g0] * HD;
  const size_t tokA1 = (size_t)row_tok[g1] * HD;
  const size_t bB0 = ((size_t)e * NI + i0 + rr0) * HD;
  const size_t bB1 = ((size_t)e * NI + i0 + rr1) * HD;
  const int ldsA = w * 1024;

  f32x4 zero = {0.f, 0.f, 0.f, 0.f};
  f32x4 accg[4][4], accu[4][4];
#pragma unroll
  for (int a = 0; a < 4; a++)
#pragma unroll
    for (int b = 0; b < 4; b++) { accg[a][b] = zero; accu[a][b] = zero; }

  auto stage = [&](int buf, int ks) {
    const int k0 = ks * 32;
    char* base = smem + buf * 24576;
    gload_lds16(xbf + tokA0 + k0 + q0 * 8, base + ldsA);
    gload_lds16(xbf + tokA1 + k0 + q1 * 8, base + ldsA + 4096);
    gload_lds16(Wgt + bB0 + k0 + q0 * 8, base + 8192 + ldsA);
    gload_lds16(Wgt + bB1 + k0 + q1 * 8, base + 8192 + ldsA + 4096);
    gload_lds16(Wut + bB0 + k0 + q0 * 8, base + 16384 + ldsA);
    gload_lds16(Wut + bB1 + k0 + q1 * 8, base + 16384 + ldsA + 4096);
  };
  const int rl = lane & 15, kslot = lane >> 4;
  auto compute = [&](int buf) {
    const char* base = smem + buf * 24576;
    bf16x8 af[4], bg[4], bu[4];
#pragma unroll
    for (int mi = 0; mi < 4; mi++) {
      int rr = wr * 64 + mi * 16 + rl;
      int byt = rr * 64 + ((kslot ^ ((rr >> 1) & 3)) << 4);
      af[mi] = *(const bf16x8*)(base + byt);
    }
#pragma unroll
    for (int ni = 0; ni < 4; ni++) {
      int rr = wc * 64 + ni * 16 + rl;
      int byt = rr * 64 + ((kslot ^ ((rr >> 1) & 3)) << 4);
      bg[ni] = *(const bf16x8*)(base + 8192 + byt);
      bu[ni] = *(const bf16x8*)(base + 16384 + byt);
    }
#pragma unroll
    for (int mi = 0; mi < 4; mi++)
#pragma unroll
      for (int ni = 0; ni < 4; ni++) {
        accg[mi][ni] = __builtin_amdgcn_mfma_f32_16x16x32_bf16(af[mi], bg[ni], accg[mi][ni], 0, 0, 0);
        accu[mi][ni] = __builtin_amdgcn_mfma_f32_16x16x32_bf16(af[mi], bu[ni], accu[mi][ni], 0, 0, 0);
      }
  };

  stage(0, 0);
  stage(1, 1);
  const int NKS = HD / 32;
  for (int ks = 0; ks < NKS; ks++) {
    if (ks < NKS - 1) {
      S_WAITCNT_VMCNT(6);    // tile ks landed (own); <=2 younger stages fly
    } else {
      S_WAITCNT_VMCNT(0);
    }
    wave_barrier();          // all waves: tile ks ready AND compute(ks-1) done
    if (ks + 2 < NKS) stage((ks + 2) % 3, ks + 2);
    compute(ks % 3);
  }

  const int rh = lane >> 4;
#pragma unroll
  for (int mi = 0; mi < 4; mi++)
#pragma unroll
    for (int ni = 0; ni < 4; ni++)
#pragma unroll
      for (int j = 0; j < 4; j++) {
        int grow = rowbase + wr * 64 + mi * 16 + rh * 4 + j;
        if (grow < rowend) {
          int gcol = i0 + wc * 64 + ni * 16 + rl;
          float g = accg[mi][ni][j], u = accu[mi][ni][j];
          float val = g / (1.f + __expf(-g)) * u;
          act[(size_t)grow * NI + gcol] = f2bf(val);
        }
      }
}

// ---------------- grouped GEMM 2: y[row] = act[row] @ Wd  (no atomics) ------
// Same one-barrier depth-3 schedule.  LDS 3 x 16KB = 48KB, 3 blocks/CU.
__launch_bounds__(256, 3)
__global__ void gemm2_kernel(const unsigned short* __restrict__ act,
                             const unsigned short* __restrict__ Wdt,
                             unsigned short* __restrict__ y,
                             const int* __restrict__ cnt) {
  const int f = blockIdx.x + 16 * (blockIdx.y + 32 * blockIdx.z);
  const int e = f & 7;
  const int rem = f >> 3;          // 0..511
  const int nt = rem >> 5;         // 0..15
  const int mt = rem & 31;         // 0..31
  const int c = cnt[e];
  if (mt * 128 >= c) return;
  const int off = cnt[8 + e];
  const int rowbase = off + mt * 128, rowend = off + c;
  const int n0 = nt * 128;
  __shared__ __align__(16) char smem[49152];
  const int lane = threadIdx.x & 63, w = threadIdx.x >> 6;
  const int wr = w >> 1, wc = w & 1;

  const int rr0 = w * 16 + (lane >> 2);
  const int rr1 = rr0 + 64;
  const int q0 = (lane & 3) ^ ((rr0 >> 1) & 3);
  const int q1 = (lane & 3) ^ ((rr1 >> 1) & 3);
  int g0 = rowbase + rr0; if (g0 > rowend - 1) g0 = rowend - 1;
  int g1 = rowbase + rr1; if (g1 > rowend - 1) g1 = rowend - 1;
  const size_t aA0 = (size_t)g0 * NI;
  const size_t aA1 = (size_t)g1 * NI;
  const size_t bB0 = ((size_t)e * HD + n0 + rr0) * NI;
  const size_t bB1 = ((size_t)e * HD + n0 + rr1) * NI;
  const int ldsA = w * 1024;

  f32x4 zero = {0.f, 0.f, 0.f, 0.f};
  f32x4 acc[4][4];
#pragma unroll
  for (int a = 0; a < 4; a++)
#pragma unroll
    for (int b = 0; b < 4; b++) acc[a][b] = zero;

  auto stage = [&](int buf, int ks) {
    const int k0 = ks * 32;
    char* base = smem + buf * 16384;
    gload_lds16(act + aA0 + k0 + q0 * 8, base + ldsA);
    gload_lds16(act + aA1 + k0 + q1 * 8, base + ldsA + 4096);
    gload_lds16(Wdt + bB0 + k0 + q0 * 8, base + 8192 + ldsA);
    gload_lds16(Wdt + bB1 + k0 + q1 * 8, base + 8192 + ldsA + 4096);
  };
  const int rl = lane & 15, kslot = lane >> 4;
  auto compute = [&](int buf) {
    const char* base = smem + buf * 16384;
    bf16x8 af[4], bf[4];
#pragma unroll
    for (int mi = 0; mi < 4; mi++) {
      int rr = wr * 64 + mi * 16 + rl;
      int byt = rr * 64 + ((kslot ^ ((rr >> 1) & 3)) << 4);
      af[mi] = *(const bf16x8*)(base + byt);
    }
#pragma unroll
    for (int ni = 0; ni < 4; ni++) {
      int rr = wc * 64 + ni * 16 + rl;
      int byt = rr * 64 + ((kslot ^ ((rr >> 1) & 3)) << 4);
      bf[ni] = *(const bf16x8*)(base + 8192 + byt);
    }
#pragma unroll
    for (int mi = 0; mi < 4; mi++)
#pragma unroll
      for (int ni = 0; ni < 4; ni++)
        acc[mi][ni] = __builtin_amdgcn_mfma_f32_16x16x32_bf16(af[mi], bf[ni], acc[mi][ni], 0, 0, 0);
  };

  stage(0, 0);
  stage(1, 1);
  const int NKS = NI / 32;
  for (int ks = 0; ks < NKS; ks++) {
    if (ks < NKS - 1) {
      S_WAITCNT_VMCNT(4);
    } else {
      S_WAITCNT_VMCNT(0);
    }
    wave_barrier();
    if (ks + 2 < NKS) stage((ks + 2) % 3, ks + 2);
    compute(ks % 3);
  }

  const int rh = lane >> 4;
#pragma unroll
  for (int mi = 0; mi < 4; mi++)
#pragma unroll
    for (int ni = 0; ni < 4; ni++)
#pragma unroll
      for (int j = 0; j < 4; j++) {
        int grow = rowbase + wr * 64 + mi * 16 + rh * 4 + j;
        if (grow < rowend) {
          int gcol = n0 + wc * 64 + ni * 16 + rl;
          y[(size_t)grow * HD + gcol] = f2bf(acc[mi][ni][j]);
        }
      }
}

// ---------------- combine: out[t] = w0*y[r0] + w1*y[r1] ----------------
__global__ void combine_kernel(const unsigned short* __restrict__ y,
                               const int2* __restrict__ tok2row,
                               const int4* __restrict__ tokinfo,
                               float* __restrict__ out) {
  int t = blockIdx.x, tid = threadIdx.x;
  int2 rr = tok2row[t];
  int4 info = tokinfo[t];
  float w0 = __int_as_float(info.z), w1 = __int_as_float(info.w);
  ushort8 a = ((const ushort8*)(y + (size_t)rr.x * HD))[tid];
  ushort8 b = ((const ushort8*)(y + (size_t)rr.y * HD))[tid];
  float4 o0, o1;
  o0.x = w0 * bf2f(a[0]) + w1 * bf2f(b[0]);
  o0.y = w0 * bf2f(a[1]) + w1 * bf2f(b[1]);
  o0.z = w0 * bf2f(a[2]) + w1 * bf2f(b[2]);
  o0.w = w0 * bf2f(a[3]) + w1 * bf2f(b[3]);
  o1.x = w0 * bf2f(a[4]) + w1 * bf2f(b[4]);
  o1.y = w0 * bf2f(a[5]) + w1 * bf2f(b[5]);
  o1.z = w0 * bf2f(a[6]) + w1 * bf2f(b[6]);
  o1.w = w0 * bf2f(a[7]) + w1 * bf2f(b[7]);
  float4* op = (float4*)(out + (size_t)t * HD + tid * 8);
  op[0] = o0; op[1] = o1;
}

// ---------------- launch ----------------
extern "C" void kernel_launch(void* const* d_in, const int* in_sizes, int n_in,
                              void* d_out, int out_size, void* d_ws, size_t ws_size,
                              hipStream_t stream) {
  const float* x  = (const float*)d_in[0];
  const float* Wr = (const float*)d_in[1];
  const float* Wg = (const float*)d_in[2];
  const float* Wu = (const float*)d_in[3];
  const float* Wd = (const float*)d_in[4];
  float* out = (float*)d_out;
  char* ws = (char*)d_ws;

  // ws layout (bytes)
  unsigned short* xbf = (unsigned short*)(ws);                 // 16,777,216
  unsigned short* Wgt = (unsigned short*)(ws + 16777216);      // 46,137,344
  unsigned short* Wut = (unsigned short*)(ws + 62914560);      // 46,137,344
  unsigned short* Wdt = (unsigned short*)(ws + 109051904);     // 46,137,344
  unsigned short* act = (unsigned short*)(ws + 155189248);     // 23,068,672
  // y aliases Wgt: gemm1 (last reader of Wgt) completes before gemm2 writes y.
  unsigned short* yb  = (unsigned short*)(ws + 16777216);      // 33,554,432
  int4*  tokinfo      = (int4*)(ws + 178257920);               // 65,536
  int*   row_tok      = (int*)(ws + 178323456);                // 32,768
  int2*  tok2row      = (int2*)(ws + 178356224);               // 32,768
  int*   cnt          = (int*)(ws + 178388992);                // 128

  hipMemsetAsync(cnt, 0, 128, stream);

  // router (1024) + Wg/Wu r-walking transpose (704); Wd rides in gemm1.
  prepass_kernel<<<1024 + 704, 256, 0, stream>>>(
      x, Wr, Wg, Wu, out + (size_t)T_TOK * HD, xbf, Wgt, Wut, tokinfo, cnt);
  route_finalize_kernel<<<1, 1024, 0, stream>>>(tokinfo, cnt, row_tok, tok2row);

  gemm1_kernel<<<dim3(11, 32, 16), 256, 0, stream>>>(
      xbf, Wgt, Wut, Wd, Wdt, act, row_tok, cnt);
  gemm2_kernel<<<dim3(16, 32, NE), 256, 0, stream>>>(act, Wdt, yb, cnt);
  combine_kernel<<<T_TOK, 256, 0, stream>>>(yb, tok2row, tokinfo, out);
}